// Round 14
// baseline (157.616 us; speedup 1.0000x reference)
//
#include <hip/hip_runtime.h>
#include <hip/hip_bf16.h>

// Problem constants
#define B_  16
#define N_  512
#define M_  16
#define H_  8
#define D_  128
#define BN_ 8192   // B_*N_
#define NB  16     // nodes per block in main kernel

typedef __attribute__((ext_vector_type(4))) float          f32x4;
typedef __attribute__((ext_vector_type(4))) _Float16       f16x4;
typedef __attribute__((ext_vector_type(8))) unsigned short u16x8;
typedef __attribute__((ext_vector_type(8))) _Float16       f16x8;

static __device__ __forceinline__ float bf2f(__hip_bfloat16 x) { return __bfloat162float(x); }
static __device__ __forceinline__ unsigned short f2bu(float x) {
    __hip_bfloat16 b = __float2bfloat16(x);
    return *reinterpret_cast<unsigned short*>(&b);
}
static __device__ __forceinline__ float bu2f(unsigned short u) {
    return __uint_as_float(((unsigned int)u) << 16);
}

// Load/store policy: interpret float tensors as f32 or bf16.
template <bool F32>
struct Pol {
    static __device__ __forceinline__ float ld(const void* p, int i) {
        if constexpr (F32) return ((const float*)p)[i];
        else               return bf2f(((const __hip_bfloat16*)p)[i]);
    }
    static __device__ __forceinline__ float4 ld4(const void* p, int i) {  // i%4==0
        if constexpr (F32) return *(const float4*)((const float*)p + i);
        else {
            const ushort4 u = *(const ushort4*)((const unsigned short*)p + i);
            return make_float4(bu2f(u.x), bu2f(u.y), bu2f(u.z), bu2f(u.w));
        }
    }
    static __device__ __forceinline__ void ld8(const void* p, long i, float* v) {  // i%8==0
        if constexpr (F32) {
            const float4 a = *(const float4*)((const float*)p + i);
            const float4 b = *(const float4*)((const float*)p + i + 4);
            v[0]=a.x; v[1]=a.y; v[2]=a.z; v[3]=a.w;
            v[4]=b.x; v[5]=b.y; v[6]=b.z; v[7]=b.w;
        } else {
            const u16x8 u = *(const u16x8*)((const unsigned short*)p + i);
            #pragma unroll
            for (int j = 0; j < 8; ++j) v[j] = bu2f(u[j]);
        }
    }
    static __device__ __forceinline__ void st8(void* p, long i, const float* v) {  // i%8==0
        if constexpr (F32) {
            *(float4*)((float*)p + i)     = make_float4(v[0], v[1], v[2], v[3]);
            *(float4*)((float*)p + i + 4) = make_float4(v[4], v[5], v[6], v[7]);
        } else {
            u16x8 u;
            #pragma unroll
            for (int j = 0; j < 8; ++j) u[j] = f2bu(v[j]);
            *(u16x8*)((unsigned short*)p + i) = u;
        }
    }
};

// Dtype probe (verbatim): f32 buffers read as bf16 at even index give
// random-exponent garbage; genuine bf16 stays small.
static __device__ __forceinline__ bool probe_is_f32(const void* h) {
    bool is_f32 = false;
    const __hip_bfloat16* hb = (const __hip_bfloat16*)h;
    for (int i = 0; i < 128; ++i) {
        const float v = bf2f(hb[2 * i]);
        if (!(fabsf(v) < 1e4f)) is_f32 = true;
    }
    return is_f32;
}

// ---------------------------------------------------------------------------
// K0 (prep, grid 520):  [byte-identical to passing rounds 5/11/12/13]
//   blk <  512 : WeffT[o][hd] = f16( sum_e W[hd][e] * Wo[(h*128+e)][o] )
//   blk >= 512 : wsrc/wdst[h][d] = sum_e W[h][d][e] * a_{src,dst}[h][e]  (f32)
// ---------------------------------------------------------------------------
template <bool F32>
static __device__ __forceinline__ void k0_body(
        const void* __restrict__ W,  const void* __restrict__ Wo,
        const void* __restrict__ a_src, const void* __restrict__ a_dst,
        float* __restrict__ wsrc, float* __restrict__ wdst,
        _Float16* __restrict__ WeffT, float* wrow /* shared [2*128] */) {
    using P = Pol<F32>;
    const int blk = blockIdx.x;
    const int t   = threadIdx.x;
    if (blk < 512) {
        const int half = t >> 7, o = t & 127;
        const int hd = blk * 2 + half;               // hd = h*128 + d
        wrow[half * 128 + o] = P::ld(W, hd * 128 + o);
        __syncthreads();
        const int hh = hd >> 7;
        float acc = 0.f;
        #pragma unroll 8
        for (int e = 0; e < 128; ++e)
            acc += wrow[half * 128 + e] * P::ld(Wo, (hh * 128 + e) * 128 + o);
        WeffT[(size_t)o * 1024 + hd] = (_Float16)acc;
    } else {
        const int hh = blk - 512;
        const int which = t >> 7, d = t & 127;
        const void* av = which ? a_dst : a_src;
        const int wbase = hh * (D_ * D_) + d * 128;
        float acc = 0.f;
        #pragma unroll 8
        for (int e = 0; e < 128; e += 4) {
            const float4 wv = P::ld4(W, wbase + e);
            const float4 aa = P::ld4(av, hh * 128 + e);
            acc += wv.x * aa.x + wv.y * aa.y + wv.z * aa.z + wv.w * aa.w;
        }
        (which ? wdst : wsrc)[hh * 128 + d] = acc;
    }
}

__global__ __launch_bounds__(256) void k0(
        const void* W, const void* Wo, const void* a_src, const void* a_dst,
        const void* h, float* wsrc, float* wdst, _Float16* WeffT) {
    __shared__ float wrow[2 * 128];
    if (probe_is_f32(h)) k0_body<true >(W, Wo, a_src, a_dst, wsrc, wdst, WeffT, wrow);
    else                 k0_body<false>(W, Wo, a_src, a_dst, wsrc, wdst, WeffT, wrow);
}

// ---------------------------------------------------------------------------
// Main fused kernel. 16 nodes/block, 512 threads (8 waves), grid 512.
// Round-13 structure (champion, 157.2) with P2+P3 FUSED into one barrier-free
// wave-local phase:
//   - src-dots computed in-wave (owner lanes, shfl reduce + broadcast) —
//     ssrc LDS round-trip and its barrier deleted.
//   - softmax over m via 4-step shfl_xor butterfly over lane bits 1..4
//     (the 16 m-values of row r live in one wave) — serial P3 phase and its
//     2 barriers deleted.  Barriers in k_gat: 12 -> 9.
// MFMA layout (proven): A lane(lo,hi) reg j = A[lo][4*hi+j]; B = B[4*hi+j][lo];
// D reg q -> row 4*hi+q, col lo.
// ---------------------------------------------------------------------------
struct __align__(16) Smem {
    union {
        _Float16 Zh[NB][1024];                 // 32768   P4 -> G1 (f16, swizzled)
        float    wsd[2][1056];                 // 8448    [which][hh*132 + c]
        struct {
            float    ts[NB][132];              // 8448    LN1 -> FF1/FF2 (padded)
            _Float16 us[NB][260];              // 8320    FF1 -> FF2 (padded)
            float    ys[NB][132];              // 8448    FF2 -> LN2 (padded)
        } ff;
    } u;
    float hs[NB][132];                         // 8448    residual + src-dot (padded)
    union {
        float attn[NB][132];                   // 8448    [r][m*8+hh] (padded stride)
        float yln[NB][132];                    // 8448    G1 -> LN1 (padded)
    } v;
    int   nls[NB][16];                         // 1024
    int   adjs[NB][16];                        // 1024
};

template <bool F32>
static __device__ __forceinline__ void gat_body(
        Smem& s,
        const void* __restrict__ h,
        const int*  __restrict__ adj,
        const int*  __restrict__ n_list,
        const float* __restrict__ wsrc,
        const float* __restrict__ wdst,
        const _Float16* __restrict__ WeffT,
        const void* __restrict__ g1, const void* __restrict__ bb1,
        const void* __restrict__ w1, const void* __restrict__ fb1,
        const void* __restrict__ w2, const void* __restrict__ fb2,
        const void* __restrict__ g2, const void* __restrict__ bb2,
        void* __restrict__ out) {
    using P = Pol<F32>;
    const int t   = threadIdx.x;
    const int bn0 = blockIdx.x * NB;
    const int b   = bn0 >> 9;                  // 512 nodes per batch
    const int l   = t & 63;
    const int w   = t >> 6;                    // wave 0..7
    const int lo  = l & 15;
    const int hi  = l >> 4;

    // ---- P1: self rows + neighbor lists + wsrc/wdst staging (512 threads)
    {
        const int r = t >> 5, c0 = (t & 31) * 4;
        const float4 v = P::ld4(h, (bn0 + r) * 128 + c0);
        *(float4*)&s.hs[r][c0] = v;
    }
    if (t < 256) {
        const int r = t >> 4, m = t & 15;
        s.nls[r][m]  = n_list[(bn0 + r) * M_ + m] & (N_ - 1);
        s.adjs[r][m] = adj[(bn0 + r) * M_ + m];
        const int hh0 = t >> 5, c0 = (t & 31) * 4;
        *(float4*)&s.u.wsd[0][hh0 * 132 + c0] = *(const float4*)(wsrc + t * 4);
    } else {
        const int i = t - 256;
        const int hh0 = i >> 5, c0 = (i & 31) * 4;
        *(float4*)&s.u.wsd[1][hh0 * 132 + c0] = *(const float4*)(wdst + i * 4);
    }
    __syncthreads();

    // ---- P2+P3 fused: scores + in-wave softmax (barrier-free inside)
    {
        const int sub = t & 1;
        const int p   = t >> 1;
        const int r   = p >> 4, m = p & 15;    // wave w handles r in {2w, 2w+1}
        const int nbr   = s.nls[r][m];
        const int amask = s.adjs[r][m];
        const int gbase = (b * N_ + nbr) * 128 + sub * 64;
        const int lbase = sub * 64;

        // dst dots: 2 threads per edge, 8 heads inline, 64 elems each.
        float accD[8];
        #pragma unroll
        for (int hh = 0; hh < 8; ++hh) accD[hh] = 0.f;
        #pragma unroll 4
        for (int c = 0; c < 64; c += 4) {
            const float4 hv = P::ld4(h, gbase + c);
            #pragma unroll
            for (int hh = 0; hh < 8; ++hh) {
                const float4 wdv = *(const float4*)&s.u.wsd[1][hh * 132 + lbase + c];
                accD[hh] += hv.x * wdv.x + hv.y * wdv.y + hv.z * wdv.z + hv.w * wdv.w;
            }
        }
        #pragma unroll
        for (int hh = 0; hh < 8; ++hh) accD[hh] += __shfl_xor(accD[hh], 1);

        // src dots, in-wave: owner lane l -> r_o = 2w + (l>>5), hh_o = (l>>2)&7,
        // chunk c0s = (l&3)*32.  Reduce over chunk bits (xor 1, 2).
        float sacc = 0.f;
        {
            const int r_o  = 2 * w + (l >> 5);
            const int hh_o = (l >> 2) & 7;
            const int c0s  = (l & 3) * 32;
            #pragma unroll 8
            for (int c = 0; c < 32; c += 4) {
                const float4 sv = *(const float4*)&s.hs[r_o][c0s + c];
                const float4 wv = *(const float4*)&s.u.wsd[0][hh_o * 132 + c0s + c];
                sacc += sv.x * wv.x + sv.y * wv.y + sv.z * wv.z + sv.w * wv.w;
            }
            sacc += __shfl_xor(sacc, 1);
            sacc += __shfl_xor(sacc, 2);
        }

        // combine + leaky + mask, then softmax over m (lane bits 1..4)
        float x[8];
        #pragma unroll
        for (int hh = 0; hh < 8; ++hh) {
            const float sval = __shfl(sacc, (l & 32) + (hh << 2));
            float v = sval + accD[hh];
            v = v > 0.f ? v : 0.2f * v;        // leaky_relu BEFORE mask (ref order)
            if (amask == 0) v = -1e9f;
            x[hh] = v;
        }
        #pragma unroll
        for (int hh = 0; hh < 8; ++hh) {
            float mx = x[hh];
            mx = fmaxf(mx, __shfl_xor(mx, 2));
            mx = fmaxf(mx, __shfl_xor(mx, 4));
            mx = fmaxf(mx, __shfl_xor(mx, 8));
            mx = fmaxf(mx, __shfl_xor(mx, 16));
            const float e = __expf(x[hh] - mx);
            float sum = e;
            sum += __shfl_xor(sum, 2);
            sum += __shfl_xor(sum, 4);
            sum += __shfl_xor(sum, 8);
            sum += __shfl_xor(sum, 16);
            x[hh] = e * (1.f / sum);
        }
        if (sub == 0) {
            *(float4*)&s.v.attn[r][m * 8]     = make_float4(x[0], x[1], x[2], x[3]);
            *(float4*)&s.v.attn[r][m * 8 + 4] = make_float4(x[4], x[5], x[6], x[7]);
        }
    }
    __syncthreads();

    // ---- P4: Z[r][hh][d] = sum_m attn[r][m][hh] * h[nl[r][m]][d]
    //      512 threads: 32 threads/node, 4 d each.  (f16, swizzled)
    {
        const int r = t >> 5, dc = t & 31, d0 = dc * 4;
        float z[8][4];
        #pragma unroll
        for (int hh = 0; hh < 8; ++hh)
            #pragma unroll
            for (int jj = 0; jj < 4; ++jj) z[hh][jj] = 0.f;
        #pragma unroll 4
        for (int m = 0; m < 16; ++m) {
            const int nbr = s.nls[r][m];
            const float4 hv = P::ld4(h, (b * N_ + nbr) * 128 + d0);
            const float hv4[4] = { hv.x, hv.y, hv.z, hv.w };
            const float4 a0 = *(const float4*)&s.v.attn[r][m * 8];
            const float4 a1 = *(const float4*)&s.v.attn[r][m * 8 + 4];
            const float av[8] = { a0.x, a0.y, a0.z, a0.w, a1.x, a1.y, a1.z, a1.w };
            #pragma unroll
            for (int hh = 0; hh < 8; ++hh)
                #pragma unroll
                for (int jj = 0; jj < 4; ++jj) z[hh][jj] += av[hh] * hv4[jj];
        }
        char* zb = (char*)&s.u.Zh[0][0] + r * 2048;
        const int xo = (r & 7) << 4;
        #pragma unroll
        for (int hh = 0; hh < 8; ++hh) {
            f16x4 vv;
            #pragma unroll
            for (int jj = 0; jj < 4; ++jj) vv[jj] = (_Float16)z[hh][jj];
            *(f16x4*)(zb + ((hh * 256 + dc * 8) ^ xo)) = vv;
        }
    }
    __syncthreads();

    // ---- G1: yln = Zh @ WeffT^T + hs   (MFMA 16x16x16, K=1024; 8 waves x 16 cols)
    {
        const char* za  = (const char*)&s.u.Zh[0][0] + lo * 2048;
        const int   xo  = (lo & 7) << 4;
        const char* wb0 = (const char*)(WeffT + (size_t)(w * 16 + lo) * 1024);
        f32x4 acc0 = {0.f, 0.f, 0.f, 0.f};
        #pragma unroll 8
        for (int ks = 0; ks < 64; ++ks) {
            const int kb = ks * 32 + hi * 8;           // byte offset of k = ks*16 + hi*4
            const f16x4 a  = *(const f16x4*)(za + (kb ^ xo));
            const f16x4 b0 = *(const f16x4*)(wb0 + kb);
            acc0 = __builtin_amdgcn_mfma_f32_16x16x16f16(a, b0, acc0, 0, 0, 0);
        }
        const int o0 = w * 16 + lo;
        #pragma unroll
        for (int q = 0; q < 4; ++q) {
            const int rr = hi * 4 + q;
            s.v.yln[rr][o0] = acc0[q] + s.hs[rr][o0];
        }
    }
    __syncthreads();

    // ---- LN1 -> ts (f32, padded rows). 16 threads per row (256 threads).
    if (t < NB * 16) {
        const int r = t >> 4, j0 = (t & 15) * 8;
        const float4 x0 = *(const float4*)&s.v.yln[r][j0];
        const float4 x1 = *(const float4*)&s.v.yln[r][j0 + 4];
        const float x[8] = { x0.x, x0.y, x0.z, x0.w, x1.x, x1.y, x1.z, x1.w };
        float sm = 0.f, ss = 0.f;
        #pragma unroll
        for (int j = 0; j < 8; ++j) { sm += x[j]; ss += x[j] * x[j]; }
        #pragma unroll
        for (int off = 8; off > 0; off >>= 1) {
            sm += __shfl_xor(sm, off);
            ss += __shfl_xor(ss, off);
        }
        const float mu   = sm * (1.f / 128.f);
        const float var  = ss * (1.f / 128.f) - mu * mu;
        const float rstd = rsqrtf(var + 1e-5f);
        float gv[8], bv[8];
        P::ld8(g1, j0, gv);
        P::ld8(bb1, j0, bv);
        #pragma unroll
        for (int j = 0; j < 8; ++j)
            s.u.ff.ts[r][j0 + j] = (x[j] - mu) * rstd * gv[j] + bv[j];
    }
    __syncthreads();

    // ---- FF1: us = relu(ts @ w1 + b1)  (MFMA; 8 waves x 32 cols; K=128)
    {
        f32x4 acc[2] = { {0.f,0.f,0.f,0.f}, {0.f,0.f,0.f,0.f} };
        #pragma unroll
        for (int ks = 0; ks < 8; ++ks) {
            const int k = ks * 16 + hi * 4;
            const float4 tv = *(const float4*)&s.u.ff.ts[lo][k];
            f16x4 a;
            a[0] = (_Float16)tv.x; a[1] = (_Float16)tv.y;
            a[2] = (_Float16)tv.z; a[3] = (_Float16)tv.w;
            #pragma unroll
            for (int nt = 0; nt < 2; ++nt) {
                const int o = w * 32 + nt * 16 + lo;
                f16x4 bb;
                #pragma unroll
                for (int j = 0; j < 4; ++j) bb[j] = (_Float16)P::ld(w1, (k + j) * 256 + o);
                acc[nt] = __builtin_amdgcn_mfma_f32_16x16x16f16(a, bb, acc[nt], 0, 0, 0);
            }
        }
        #pragma unroll
        for (int nt = 0; nt < 2; ++nt) {
            const int o = w * 32 + nt * 16 + lo;
            const float bias = P::ld(fb1, o);
            #pragma unroll
            for (int q = 0; q < 4; ++q)
                s.u.ff.us[hi * 4 + q][o] = (_Float16)fmaxf(acc[nt][q] + bias, 0.f);
        }
    }
    __syncthreads();

    // ---- FF2: ys = us @ w2 + b2 + ts  (MFMA; 8 waves x 16 cols; K=256)
    {
        const int o0 = w * 16 + lo;
        f32x4 acc = {0.f, 0.f, 0.f, 0.f};
        #pragma unroll
        for (int ks = 0; ks < 16; ++ks) {
            const int k = ks * 16 + hi * 4;
            const f16x4 a = *(const f16x4*)&s.u.ff.us[lo][k];
            f16x4 bb;
            #pragma unroll
            for (int j = 0; j < 4; ++j) bb[j] = (_Float16)P::ld(w2, (k + j) * 128 + o0);
            acc = __builtin_amdgcn_mfma_f32_16x16x16f16(a, bb, acc, 0, 0, 0);
        }
        const float bias = P::ld(fb2, o0);
        #pragma unroll
        for (int q = 0; q < 4; ++q) {
            const int rr = hi * 4 + q;
            s.u.ff.ys[rr][o0] = acc[q] + bias + s.u.ff.ts[rr][o0];
        }
    }
    __syncthreads();

    // ---- LN2 -> out. 16 threads per row (256 threads).
    if (t < NB * 16) {
        const int r = t >> 4, j0 = (t & 15) * 8;
        const float4 x0 = *(const float4*)&s.u.ff.ys[r][j0];
        const float4 x1 = *(const float4*)&s.u.ff.ys[r][j0 + 4];
        const float x[8] = { x0.x, x0.y, x0.z, x0.w, x1.x, x1.y, x1.z, x1.w };
        float sm = 0.f, ss = 0.f;
        #pragma unroll
        for (int j = 0; j < 8; ++j) { sm += x[j]; ss += x[j] * x[j]; }
        #pragma unroll
        for (int off = 8; off > 0; off >>= 1) {
            sm += __shfl_xor(sm, off);
            ss += __shfl_xor(ss, off);
        }
        const float mu   = sm * (1.f / 128.f);
        const float var  = ss * (1.f / 128.f) - mu * mu;
        const float rstd = rsqrtf(var + 1e-5f);
        float gv[8], bv[8], o8[8];
        P::ld8(g2, j0, gv);
        P::ld8(bb2, j0, bv);
        #pragma unroll
        for (int j = 0; j < 8; ++j) o8[j] = (x[j] - mu) * rstd * gv[j] + bv[j];
        P::st8(out, (long)(bn0 + r) * 128 + j0, o8);
    }
}

__global__ __launch_bounds__(512) void k_gat(
        const void* __restrict__ h,
        const int*  __restrict__ adj,
        const int*  __restrict__ n_list,
        const float* __restrict__ wsrc,
        const float* __restrict__ wdst,
        const _Float16* __restrict__ WeffT,
        const void* __restrict__ g1, const void* __restrict__ bb1,
        const void* __restrict__ w1, const void* __restrict__ fb1,
        const void* __restrict__ w2, const void* __restrict__ fb2,
        const void* __restrict__ g2, const void* __restrict__ bb2,
        void* __restrict__ out) {
    __shared__ Smem s;
    if (probe_is_f32(h))
        gat_body<true >(s, h, adj, n_list, wsrc, wdst, WeffT,
                        g1, bb1, w1, fb1, w2, fb2, g2, bb2, out);
    else
        gat_body<false>(s, h, adj, n_list, wsrc, wdst, WeffT,
                        g1, bb1, w1, fb1, w2, fb2, g2, bb2, out);
}

// ---------------------------------------------------------------------------
extern "C" void kernel_launch(void* const* d_in, const int* in_sizes, int n_in,
                              void* d_out, int out_size, void* d_ws, size_t ws_size,
                              hipStream_t stream) {
    (void)in_sizes; (void)n_in; (void)out_size; (void)ws_size;

    // ws layout (bytes):
    //   wsrc   [     0,   4096)  f32[1024]
    //   wdst   [  4096,   8192)  f32[1024]
    //   WeffT  [  8192, 270336)  f16[128][1024]
    char* wsb = (char*)d_ws;
    float*     wsrc  = (float*)(wsb);
    float*     wdst  = (float*)(wsb + 4096);
    _Float16*  WeffT = (_Float16*)(wsb + 8192);

    k0<<<520, 256, 0, stream>>>(d_in[3], d_in[6], d_in[4], d_in[5], d_in[0],
                                wsrc, wdst, WeffT);
    k_gat<<<BN_ / NB, 512, 0, stream>>>(
        d_in[0], (const int*)d_in[1], (const int*)d_in[2], wsrc, wdst, WeffT,
        d_in[7], d_in[8], d_in[9], d_in[10], d_in[11], d_in[12],
        d_in[13], d_in[14], d_out);
}